// Round 18
// baseline (33.523 us; speedup 1.0000x reference)
//
#include <hip/hip_runtime.h>
#include <hip/hip_bf16.h>
#include <math.h>

// AFM: B=4096, F=24, D=64, A=64, P=F*(F-1)/2=276
#define NF 24
#define ND 64
#define NA 64
#define NP 276
#define NPAD 288
#define NTILE 18
#define NT 256      // 4 waves per block; wave w handles batch blockIdx*4+w
#define BPB 4
#define XPITCH 72   // fp16 row pitch

typedef _Float16 f16x8 __attribute__((ext_vector_type(8)));
typedef _Float16 f16x4 __attribute__((ext_vector_type(4)));
typedef _Float16 f16x2 __attribute__((ext_vector_type(2)));
typedef float    f32x4 __attribute__((ext_vector_type(4)));

// ---- DPP helpers for the final wave-wide softmax reduce ----
template <int CTRL, int RMASK>
__device__ __forceinline__ float dpp_add_step(float v) {
    int moved = __builtin_amdgcn_update_dpp(0, __float_as_int(v), CTRL, RMASK, 0xf, true);
    return v + __int_as_float(moved);
}
template <int CTRL, int RMASK>
__device__ __forceinline__ float dpp_max_step(float v) {
    int moved = __builtin_amdgcn_update_dpp(__float_as_int(v), __float_as_int(v), CTRL, RMASK, 0xf, false);
    return fmaxf(v, __int_as_float(moved));
}
__device__ __forceinline__ float wave_sum(float v) {
    v = dpp_add_step<0x111, 0xf>(v);   // row_shr 1
    v = dpp_add_step<0x112, 0xf>(v);   // row_shr 2
    v = dpp_add_step<0x114, 0xf>(v);   // row_shr 4
    v = dpp_add_step<0x118, 0xf>(v);   // row_shr 8
    v = dpp_add_step<0x142, 0xa>(v);   // row_bcast:15 -> rows 1,3
    v = dpp_add_step<0x143, 0xc>(v);   // row_bcast:31 -> rows 2,3
    return __int_as_float(__builtin_amdgcn_readlane(__float_as_int(v), 63));
}
__device__ __forceinline__ float wave_max(float v) {
    v = dpp_max_step<0x111, 0xf>(v);
    v = dpp_max_step<0x112, 0xf>(v);
    v = dpp_max_step<0x114, 0xf>(v);
    v = dpp_max_step<0x118, 0xf>(v);
    v = dpp_max_step<0x142, 0xa>(v);
    v = dpp_max_step<0x143, 0xc>(v);
    return __int_as_float(__builtin_amdgcn_readlane(__float_as_int(v), 63));
}

__device__ __forceinline__ float fdot2(f16x2 a, f16x2 b, float c) {
#if __has_builtin(__builtin_amdgcn_fdot2)
    return __builtin_amdgcn_fdot2(a, b, c, false);
#else
    return fmaf((float)a[1], (float)b[1], fmaf((float)a[0], (float)b[0], c));
#endif
}

// ws layout (16-bit units):
//   [0, 4096)    waF: [lane 64][chunk 8 = nt*2+kh][8 f16]
//   [4096, 4160) wfc: f16[64] in d-order
__global__ __launch_bounds__(64) void afm_prep_kernel(
    const float* __restrict__ Wa,
    const float* __restrict__ Wfc,
    unsigned short* __restrict__ ws)
{
    const int l  = (int)threadIdx.x;
    const int lg = l >> 4, li = l & 15;
    _Float16* waF = (_Float16*)ws;
    _Float16* wfc = (_Float16*)(ws + 64 * 64);
    #pragma unroll
    for (int nt = 0; nt < 4; ++nt)
        #pragma unroll
        for (int kh = 0; kh < 2; ++kh)
            #pragma unroll
            for (int i = 0; i < 8; ++i) {
                int d = kh * 32 + lg * 8 + i;
                waF[l * 64 + (nt * 2 + kh) * 8 + i] = (_Float16)Wa[d * NA + nt * 16 + li];
            }
    wfc[l] = (_Float16)Wfc[l];
}

__global__ __launch_bounds__(NT) void afm_mfma_kernel(
    const float* __restrict__ x,
    const float* __restrict__ ba,
    const float* __restrict__ Wp,
    const float* __restrict__ bfc,
    const unsigned short* __restrict__ ws,
    float* __restrict__ out)
{
    const int tid  = (int)threadIdx.x;
    const int lane = tid & 63;
    const int wid  = tid >> 6;
    const int b    = blockIdx.x * BPB + wid;   // this wave's batch
    const int lg   = lane >> 4;
    const int li   = lane & 15;

    __shared__ _Float16 xs[BPB][NF][XPITCH];   // per-wave fp16 x tile
    __shared__ float    lsums[BPB][NPAD][4];   // per-pair partial logits by lg
    __shared__ float    vvs[BPB][NPAD];        // per-pair v (written by lg0)

    // ---- stage x[b] into LDS as fp16 (cvt once here) ----
    const float4* xb4 = (const float4*)(x + (size_t)b * (NF * ND));
    #pragma unroll
    for (int k = 0; k < 6; ++k) {
        int i = lane + k * 64;           // 0..383 float4s
        float4 v = xb4[i];
        f16x4 hv = { (_Float16)v.x, (_Float16)v.y, (_Float16)v.z, (_Float16)v.w };
        *(f16x4*)&xs[wid][i >> 4][(i & 15) * 4] = hv;   // 8B-aligned
    }

    // ---- fragments from ws: 8+2 vector loads, no cvt ----
    const f16x8* waF  = (const f16x8*)ws;              // [64][8]
    const f16x8* wfcP = (const f16x8*)(ws + 64 * 64);  // [8] (64 f16 d-order)
    f16x8 WaF[4][2];
    #pragma unroll
    for (int nt = 0; nt < 4; ++nt)
        #pragma unroll
        for (int kh = 0; kh < 2; ++kh)
            WaF[nt][kh] = waF[lane * 8 + nt * 2 + kh];
    f16x8 WfcR[2] = { wfcP[lg], wfcP[4 + lg] };        // d = kh*32 + lg*8 + i

    // per-lane unit arrays: unit = nt*16 + lg*4 + j  (C/D row under swapped MFMA)
    float ba_t[4][4], wp_t[4][4];
    #pragma unroll
    for (int nt = 0; nt < 4; ++nt)
        #pragma unroll
        for (int j = 0; j < 4; ++j) {
            ba_t[nt][j] = ba[nt * 16 + lg * 4 + j];
            wp_t[nt][j] = Wp[nt * 16 + lg * 4 + j];
        }

    // ---- pair table: closed-form triu inversion (no memory; r17-verified) ----
    int prt[NTILE];
    #pragma unroll
    for (int t = 0; t < NTILE; ++t) {
        int p = t * 16 + li;
        if (p > NP - 1) p = NP - 1;                 // pad lanes: harmless dup
        float disc = (float)(2209 - 8 * p);
        int r = (int)((47.0f - sqrtf(disc)) * 0.5f);
        int S = (r * (47 - r)) >> 1;
        if (p < S) { --r; S = (r * (47 - r)) >> 1; }
        else { int S1 = ((r + 1) * (46 - r)) >> 1; if (p >= S1) { ++r; S = S1; } }
        int c = r + 1 + (p - S);
        prt[t] = (r << 16) | c;
    }

    // in-wave ordering of staging writes vs tile reads
    asm volatile("s_waitcnt lgkmcnt(0)" ::: "memory");

    // ---- skewed pipeline: tile t MFMAs in flight while epilogue of t-1 runs ----
    f32x4 accP[4];
    float vpP;

    // prologue: tile 0 loads + MFMAs + v-dot
    {
        int pr = prt[0];
        int rI = pr >> 16, cI = pr & 0xffff;
        f16x8 Ah[2];
        #pragma unroll
        for (int kh = 0; kh < 2; ++kh) {
            int d0 = kh * 32 + lg * 8;
            f16x8 rv = *(const f16x8*)&xs[wid][rI][d0];
            f16x8 cv = *(const f16x8*)&xs[wid][cI][d0];
            Ah[kh] = rv * cv;
        }
        #pragma unroll
        for (int nt = 0; nt < 4; ++nt) {
            accP[nt] = (f32x4){ba_t[nt][0], ba_t[nt][1], ba_t[nt][2], ba_t[nt][3]};
            accP[nt] = __builtin_amdgcn_mfma_f32_16x16x32_f16(WaF[nt][0], Ah[0], accP[nt], 0, 0, 0);
            accP[nt] = __builtin_amdgcn_mfma_f32_16x16x32_f16(WaF[nt][1], Ah[1], accP[nt], 0, 0, 0);
        }
        float vp = 0.f;
        #pragma unroll
        for (int kh = 0; kh < 2; ++kh)
            #pragma unroll
            for (int i = 0; i < 4; ++i) {
                f16x2 a = { Ah[kh][2 * i], Ah[kh][2 * i + 1] };
                f16x2 w = { WfcR[kh][2 * i], WfcR[kh][2 * i + 1] };
                vp = fdot2(a, w, vp);
            }
        vpP = vp;
    }

    #pragma unroll
    for (int t = 1; t <= NTILE; ++t) {
        f32x4 accC[4];
        float vpC = 0.f;
        if (t < NTILE) {
            // issue tile t loads + MFMAs + v-dot (VALU, parallel to MFMA pipe)
            int pr = prt[t];
            int rI = pr >> 16, cI = pr & 0xffff;
            f16x8 Ah[2];
            #pragma unroll
            for (int kh = 0; kh < 2; ++kh) {
                int d0 = kh * 32 + lg * 8;
                f16x8 rv = *(const f16x8*)&xs[wid][rI][d0];
                f16x8 cv = *(const f16x8*)&xs[wid][cI][d0];
                Ah[kh] = rv * cv;
            }
            #pragma unroll
            for (int nt = 0; nt < 4; ++nt) {
                accC[nt] = (f32x4){ba_t[nt][0], ba_t[nt][1], ba_t[nt][2], ba_t[nt][3]};
                accC[nt] = __builtin_amdgcn_mfma_f32_16x16x32_f16(WaF[nt][0], Ah[0], accC[nt], 0, 0, 0);
                accC[nt] = __builtin_amdgcn_mfma_f32_16x16x32_f16(WaF[nt][1], Ah[1], accC[nt], 0, 0, 0);
            }
            float vp = 0.f;
            #pragma unroll
            for (int kh = 0; kh < 2; ++kh)
                #pragma unroll
                for (int i = 0; i < 4; ++i) {
                    f16x2 a = { Ah[kh][2 * i], Ah[kh][2 * i + 1] };
                    f16x2 w = { WfcR[kh][2 * i], WfcR[kh][2 * i + 1] };
                    vp = fdot2(a, w, vp);
                }
            vpC = vp;
        }

        // epilogue for tile t-1, overlapped with tile t MFMAs:
        {
            float s0 = 0.f, s1 = 0.f, s2 = 0.f, s3 = 0.f;
            #pragma unroll
            for (int j = 0; j < 4; ++j) {
                s0 = fmaf(fmaxf(accP[0][j], 0.f), wp_t[0][j], s0);
                s1 = fmaf(fmaxf(accP[1][j], 0.f), wp_t[1][j], s1);
                s2 = fmaf(fmaxf(accP[2][j], 0.f), wp_t[2][j], s2);
                s3 = fmaf(fmaxf(accP[3][j], 0.f), wp_t[3][j], s3);
            }
            float lsum = (s0 + s1) + (s2 + s3);
            int row = (t - 1) * 16 + li;
            lsums[wid][row][lg] = lsum;          // 2 lanes/bank: conflict-free
            float vv = vpP;                      // cross-lg sum (MFMA-shadowed)
            vv += __shfl_xor(vv, 16);
            vv += __shfl_xor(vv, 32);
            if (lg == 0)
                vvs[wid][row] = vv;
        }

        if (t < NTILE) {
            #pragma unroll
            for (int nt = 0; nt < 4; ++nt) accP[nt] = accC[nt];
            vpP = vpC;
        }
    }

    asm volatile("s_waitcnt lgkmcnt(0)" ::: "memory");

    // ---- per-wave softmax fused with output (combine lg-partials here) ----
    float2 myv[5];
    float m = -INFINITY;
    #pragma unroll
    for (int k = 0; k < 5; ++k) {
        int p = lane + k * 64;
        if (p < NP) {
            float4 ls = *(const float4*)&lsums[wid][p][0];
            float lg4 = (ls.x + ls.y) + (ls.z + ls.w);
            myv[k] = make_float2(lg4, vvs[wid][p]);
            m = fmaxf(m, lg4);
        } else {
            myv[k] = make_float2(-INFINITY, 0.f);
        }
    }
    m = wave_max(m);

    float se = 0.f, sev = 0.f;
    #pragma unroll
    for (int k = 0; k < 5; ++k) {
        int p = lane + k * 64;
        if (p < NP) {
            float e = __expf(myv[k].x - m);
            se += e;
            sev = fmaf(e, myv[k].y, sev);
        }
    }
    se  = wave_sum(se);
    sev = wave_sum(sev);
    if (lane == 0)
        out[b] = sev / se + bfc[0];
}

extern "C" void kernel_launch(void* const* d_in, const int* in_sizes, int n_in,
                              void* d_out, int out_size, void* d_ws, size_t ws_size,
                              hipStream_t stream) {
    const float* x   = (const float*)d_in[0];
    const float* Wa  = (const float*)d_in[1];
    const float* ba  = (const float*)d_in[2];
    const float* Wp  = (const float*)d_in[3];
    // d_in[4] = bp  (unused: softmax shift-invariant)
    const float* Wfc = (const float*)d_in[5];
    const float* bfc = (const float*)d_in[6];
    float* out = (float*)d_out;
    unsigned short* ws = (unsigned short*)d_ws;

    const int B = in_sizes[0] / (NF * ND);
    hipLaunchKernelGGL(afm_prep_kernel, dim3(1), dim3(64), 0, stream, Wa, Wfc, ws);
    hipLaunchKernelGGL(afm_mfma_kernel, dim3(B / BPB), dim3(NT), 0, stream,
                       x, ba, Wp, bfc, ws, out);
}

// Round 19
// 32.961 us; speedup vs baseline: 1.0171x; 1.0171x over previous
//
#include <hip/hip_runtime.h>
#include <hip/hip_bf16.h>
#include <math.h>

// AFM: B=4096, F=24, D=64, A=64, P=F*(F-1)/2=276
#define NF 24
#define ND 64
#define NA 64
#define NP 276
#define NPAD 288
#define NTILE 18
#define NT 256      // 4 waves per block; wave w handles batch blockIdx*4+w
#define BPB 4
#define XPITCH 72   // fp16 row pitch

typedef _Float16 f16x8 __attribute__((ext_vector_type(8)));
typedef _Float16 f16x4 __attribute__((ext_vector_type(4)));
typedef float    f32x4 __attribute__((ext_vector_type(4)));

// ---- DPP helpers for the final wave-wide softmax reduce ----
template <int CTRL, int RMASK>
__device__ __forceinline__ float dpp_add_step(float v) {
    int moved = __builtin_amdgcn_update_dpp(0, __float_as_int(v), CTRL, RMASK, 0xf, true);
    return v + __int_as_float(moved);
}
template <int CTRL, int RMASK>
__device__ __forceinline__ float dpp_max_step(float v) {
    int moved = __builtin_amdgcn_update_dpp(__float_as_int(v), __float_as_int(v), CTRL, RMASK, 0xf, false);
    return fmaxf(v, __int_as_float(moved));
}
__device__ __forceinline__ float wave_sum(float v) {
    v = dpp_add_step<0x111, 0xf>(v);   // row_shr 1
    v = dpp_add_step<0x112, 0xf>(v);   // row_shr 2
    v = dpp_add_step<0x114, 0xf>(v);   // row_shr 4
    v = dpp_add_step<0x118, 0xf>(v);   // row_shr 8
    v = dpp_add_step<0x142, 0xa>(v);   // row_bcast:15 -> rows 1,3
    v = dpp_add_step<0x143, 0xc>(v);   // row_bcast:31 -> rows 2,3
    return __int_as_float(__builtin_amdgcn_readlane(__float_as_int(v), 63));
}
__device__ __forceinline__ float wave_max(float v) {
    v = dpp_max_step<0x111, 0xf>(v);
    v = dpp_max_step<0x112, 0xf>(v);
    v = dpp_max_step<0x114, 0xf>(v);
    v = dpp_max_step<0x118, 0xf>(v);
    v = dpp_max_step<0x142, 0xa>(v);
    v = dpp_max_step<0x143, 0xc>(v);
    return __int_as_float(__builtin_amdgcn_readlane(__float_as_int(v), 63));
}

// ws layout (16-bit units):
//   [0, 4096)    waF:  [lane 64][chunk 8 = nt*2+kh][8 f16]
//   [4096, 5120) wfcF: [lane 64][kh 2][8 f16]  (row0=hi, row1=lo as A-operand)
__global__ __launch_bounds__(64) void afm_prep_kernel(
    const float* __restrict__ Wa,
    const float* __restrict__ Wfc,
    unsigned short* __restrict__ ws)
{
    const int l  = (int)threadIdx.x;
    const int lg = l >> 4, li = l & 15;
    _Float16* waF  = (_Float16*)ws;
    _Float16* wfcF = (_Float16*)(ws + 64 * 64);
    #pragma unroll
    for (int nt = 0; nt < 4; ++nt)
        #pragma unroll
        for (int kh = 0; kh < 2; ++kh)
            #pragma unroll
            for (int i = 0; i < 8; ++i) {
                int d = kh * 32 + lg * 8 + i;
                waF[l * 64 + (nt * 2 + kh) * 8 + i] = (_Float16)Wa[d * NA + nt * 16 + li];
            }
    #pragma unroll
    for (int kh = 0; kh < 2; ++kh)
        #pragma unroll
        for (int i = 0; i < 8; ++i) {
            int d = kh * 32 + lg * 8 + i;
            float w = Wfc[d];
            _Float16 hi = (_Float16)w;
            _Float16 lo = (_Float16)(w - (float)hi);
            wfcF[l * 16 + kh * 8 + i] = (li == 0) ? hi : ((li == 1) ? lo : (_Float16)0.f);
        }
}

__global__ __launch_bounds__(NT) void afm_mfma_kernel(
    const float* __restrict__ x,
    const float* __restrict__ ba,
    const float* __restrict__ Wp,
    const float* __restrict__ bfc,
    const unsigned short* __restrict__ ws,
    float* __restrict__ out)
{
    const int tid  = (int)threadIdx.x;
    const int lane = tid & 63;
    const int wid  = tid >> 6;
    const int b    = blockIdx.x * BPB + wid;   // this wave's batch
    const int lg   = lane >> 4;
    const int li   = lane & 15;

    __shared__ _Float16 xs[BPB][NF][XPITCH];   // per-wave fp16 x tile
    __shared__ float    lsums[BPB][NPAD][4];   // per-pair partial logits by lg
    __shared__ float    vvs[BPB][NPAD];        // per-pair v (written by lg0)

    // ---- stage x[b] into LDS as fp16 (cvt once here) ----
    const float4* xb4 = (const float4*)(x + (size_t)b * (NF * ND));
    #pragma unroll
    for (int k = 0; k < 6; ++k) {
        int i = lane + k * 64;           // 0..383 float4s
        float4 v = xb4[i];
        f16x4 hv = { (_Float16)v.x, (_Float16)v.y, (_Float16)v.z, (_Float16)v.w };
        *(f16x4*)&xs[wid][i >> 4][(i & 15) * 4] = hv;   // 8B-aligned
    }

    // ---- fragments from ws: 10 vector loads, no cvt ----
    const f16x8* waF  = (const f16x8*)ws;              // [64][8]
    const f16x8* wfcF = (const f16x8*)(ws + 64 * 64);  // [64][2]
    f16x8 WaF[4][2];
    #pragma unroll
    for (int nt = 0; nt < 4; ++nt)
        #pragma unroll
        for (int kh = 0; kh < 2; ++kh)
            WaF[nt][kh] = waF[lane * 8 + nt * 2 + kh];
    f16x8 WfcF[2] = { wfcF[lane * 2 + 0], wfcF[lane * 2 + 1] };

    // per-lane unit arrays: unit = nt*16 + lg*4 + j  (C/D row under swapped MFMA)
    float ba_t[4][4], wp_t[4][4];
    #pragma unroll
    for (int nt = 0; nt < 4; ++nt)
        #pragma unroll
        for (int j = 0; j < 4; ++j) {
            ba_t[nt][j] = ba[nt * 16 + lg * 4 + j];
            wp_t[nt][j] = Wp[nt * 16 + lg * 4 + j];
        }

    // ---- pair table: closed-form triu inversion (no memory; r17-verified) ----
    int prt[NTILE];
    #pragma unroll
    for (int t = 0; t < NTILE; ++t) {
        int p = t * 16 + li;
        if (p > NP - 1) p = NP - 1;                 // pad lanes: harmless dup
        float disc = (float)(2209 - 8 * p);
        int r = (int)((47.0f - sqrtf(disc)) * 0.5f);
        int S = (r * (47 - r)) >> 1;
        if (p < S) { --r; S = (r * (47 - r)) >> 1; }
        else { int S1 = ((r + 1) * (46 - r)) >> 1; if (p >= S1) { ++r; S = S1; } }
        int c = r + 1 + (p - S);
        prt[t] = (r << 16) | c;
    }

    // in-wave ordering of staging writes vs tile reads
    asm volatile("s_waitcnt lgkmcnt(0)" ::: "memory");

    // ---- skewed pipeline: MFMAs of tile t in flight while epilogue of t-1 runs ----
    f32x4 accP[4], accvP;

    // prologue: tile 0 loads + MFMAs -> accP
    {
        int pr = prt[0];
        int rI = pr >> 16, cI = pr & 0xffff;
        f16x8 Ah[2];
        #pragma unroll
        for (int kh = 0; kh < 2; ++kh) {
            int d0 = kh * 32 + lg * 8;
            f16x8 rv = *(const f16x8*)&xs[wid][rI][d0];
            f16x8 cv = *(const f16x8*)&xs[wid][cI][d0];
            Ah[kh] = rv * cv;
        }
        #pragma unroll
        for (int nt = 0; nt < 4; ++nt) {
            accP[nt] = (f32x4){ba_t[nt][0], ba_t[nt][1], ba_t[nt][2], ba_t[nt][3]};
            accP[nt] = __builtin_amdgcn_mfma_f32_16x16x32_f16(WaF[nt][0], Ah[0], accP[nt], 0, 0, 0);
            accP[nt] = __builtin_amdgcn_mfma_f32_16x16x32_f16(WaF[nt][1], Ah[1], accP[nt], 0, 0, 0);
        }
        accvP = (f32x4){0.f, 0.f, 0.f, 0.f};
        accvP = __builtin_amdgcn_mfma_f32_16x16x32_f16(WfcF[0], Ah[0], accvP, 0, 0, 0);
        accvP = __builtin_amdgcn_mfma_f32_16x16x32_f16(WfcF[1], Ah[1], accvP, 0, 0, 0);
    }

    #pragma unroll
    for (int t = 1; t <= NTILE; ++t) {
        f32x4 accC[4], accvC;
        if (t < NTILE) {
            // issue tile t loads + MFMAs
            int pr = prt[t];
            int rI = pr >> 16, cI = pr & 0xffff;
            f16x8 Ah[2];
            #pragma unroll
            for (int kh = 0; kh < 2; ++kh) {
                int d0 = kh * 32 + lg * 8;
                f16x8 rv = *(const f16x8*)&xs[wid][rI][d0];
                f16x8 cv = *(const f16x8*)&xs[wid][cI][d0];
                Ah[kh] = rv * cv;
            }
            #pragma unroll
            for (int nt = 0; nt < 4; ++nt) {
                accC[nt] = (f32x4){ba_t[nt][0], ba_t[nt][1], ba_t[nt][2], ba_t[nt][3]};
                accC[nt] = __builtin_amdgcn_mfma_f32_16x16x32_f16(WaF[nt][0], Ah[0], accC[nt], 0, 0, 0);
                accC[nt] = __builtin_amdgcn_mfma_f32_16x16x32_f16(WaF[nt][1], Ah[1], accC[nt], 0, 0, 0);
            }
            accvC = (f32x4){0.f, 0.f, 0.f, 0.f};
            accvC = __builtin_amdgcn_mfma_f32_16x16x32_f16(WfcF[0], Ah[0], accvC, 0, 0, 0);
            accvC = __builtin_amdgcn_mfma_f32_16x16x32_f16(WfcF[1], Ah[1], accvC, 0, 0, 0);
        }

        // epilogue for tile t-1 (accP), overlapped with tile t MFMAs:
        // tree-reduced relu+Wp dot over this lane's 16 units
        {
            float s0 = 0.f, s1 = 0.f, s2 = 0.f, s3 = 0.f;
            #pragma unroll
            for (int j = 0; j < 4; ++j) {
                s0 = fmaf(fmaxf(accP[0][j], 0.f), wp_t[0][j], s0);
                s1 = fmaf(fmaxf(accP[1][j], 0.f), wp_t[1][j], s1);
                s2 = fmaf(fmaxf(accP[2][j], 0.f), wp_t[2][j], s2);
                s3 = fmaf(fmaxf(accP[3][j], 0.f), wp_t[3][j], s3);
            }
            float lsum = (s0 + s1) + (s2 + s3);
            int row = (t - 1) * 16 + li;
            lsums[wid][row][lg] = lsum;          // 2 lanes/bank: conflict-free
            if (lg == 0)
                vvs[wid][row] = accvP[0] + accvP[1];   // rows 0(hi)+1(lo)
        }

        if (t < NTILE) {
            #pragma unroll
            for (int nt = 0; nt < 4; ++nt) accP[nt] = accC[nt];
            accvP = accvC;
        }
    }

    asm volatile("s_waitcnt lgkmcnt(0)" ::: "memory");

    // ---- per-wave softmax fused with output (combine lg-partials here) ----
    float2 myv[5];
    float m = -INFINITY;
    #pragma unroll
    for (int k = 0; k < 5; ++k) {
        int p = lane + k * 64;
        if (p < NP) {
            float4 ls = *(const float4*)&lsums[wid][p][0];
            float lg4 = (ls.x + ls.y) + (ls.z + ls.w);
            myv[k] = make_float2(lg4, vvs[wid][p]);
            m = fmaxf(m, lg4);
        } else {
            myv[k] = make_float2(-INFINITY, 0.f);
        }
    }
    m = wave_max(m);

    float se = 0.f, sev = 0.f;
    #pragma unroll
    for (int k = 0; k < 5; ++k) {
        int p = lane + k * 64;
        if (p < NP) {
            float e = __expf(myv[k].x - m);
            se += e;
            sev = fmaf(e, myv[k].y, sev);
        }
    }
    se  = wave_sum(se);
    sev = wave_sum(sev);
    if (lane == 0)
        out[b] = sev / se + bfc[0];
}

extern "C" void kernel_launch(void* const* d_in, const int* in_sizes, int n_in,
                              void* d_out, int out_size, void* d_ws, size_t ws_size,
                              hipStream_t stream) {
    const float* x   = (const float*)d_in[0];
    const float* Wa  = (const float*)d_in[1];
    const float* ba  = (const float*)d_in[2];
    const float* Wp  = (const float*)d_in[3];
    // d_in[4] = bp  (unused: softmax shift-invariant)
    const float* Wfc = (const float*)d_in[5];
    const float* bfc = (const float*)d_in[6];
    float* out = (float*)d_out;
    unsigned short* ws = (unsigned short*)d_ws;

    const int B = in_sizes[0] / (NF * ND);
    hipLaunchKernelGGL(afm_prep_kernel, dim3(1), dim3(64), 0, stream, Wa, Wfc, ws);
    hipLaunchKernelGGL(afm_mfma_kernel, dim3(B / BPB), dim3(NT), 0, stream,
                       x, ba, Wp, bfc, ws, out);
}

// Round 20
// 27.697 us; speedup vs baseline: 1.2104x; 1.1900x over previous
//
#include <hip/hip_runtime.h>
#include <hip/hip_bf16.h>
#include <math.h>

// AFM: B=4096, F=24, D=64, A=64, P=F*(F-1)/2=276
#define NF 24
#define ND 64
#define NA 64
#define NP 276
#define NPAD 288
#define NTILE 18
#define NT 256      // 4 waves per block; wave w handles batch blockIdx*4+w
#define BPB 4
#define XPITCH 72   // fp16 row pitch

typedef _Float16 f16x8 __attribute__((ext_vector_type(8)));
typedef _Float16 f16x4 __attribute__((ext_vector_type(4)));
typedef float    f32x4 __attribute__((ext_vector_type(4)));

// ---- DPP helpers for the final wave-wide softmax reduce ----
template <int CTRL, int RMASK>
__device__ __forceinline__ float dpp_add_step(float v) {
    int moved = __builtin_amdgcn_update_dpp(0, __float_as_int(v), CTRL, RMASK, 0xf, true);
    return v + __int_as_float(moved);
}
template <int CTRL, int RMASK>
__device__ __forceinline__ float dpp_max_step(float v) {
    int moved = __builtin_amdgcn_update_dpp(__float_as_int(v), __float_as_int(v), CTRL, RMASK, 0xf, false);
    return fmaxf(v, __int_as_float(moved));
}
__device__ __forceinline__ float wave_sum(float v) {
    v = dpp_add_step<0x111, 0xf>(v);   // row_shr 1
    v = dpp_add_step<0x112, 0xf>(v);   // row_shr 2
    v = dpp_add_step<0x114, 0xf>(v);   // row_shr 4
    v = dpp_add_step<0x118, 0xf>(v);   // row_shr 8
    v = dpp_add_step<0x142, 0xa>(v);   // row_bcast:15 -> rows 1,3
    v = dpp_add_step<0x143, 0xc>(v);   // row_bcast:31 -> rows 2,3
    return __int_as_float(__builtin_amdgcn_readlane(__float_as_int(v), 63));
}
__device__ __forceinline__ float wave_max(float v) {
    v = dpp_max_step<0x111, 0xf>(v);
    v = dpp_max_step<0x112, 0xf>(v);
    v = dpp_max_step<0x114, 0xf>(v);
    v = dpp_max_step<0x118, 0xf>(v);
    v = dpp_max_step<0x142, 0xa>(v);
    v = dpp_max_step<0x143, 0xc>(v);
    return __int_as_float(__builtin_amdgcn_readlane(__float_as_int(v), 63));
}

// ws layout (16-bit units):
//   [0, 4096)    waF:  [lane 64][chunk 8 = nt*2+kh][8 f16]
//   [4096, 5120) wfcF: [lane 64][kh 2][8 f16]  (row0=hi, row1=lo as A-operand)
//   [5120, 5696) rc:   288 ints, packed (r<<16)|c, pad pairs = (0,0)
__global__ __launch_bounds__(64) void afm_prep_kernel(
    const float* __restrict__ Wa,
    const float* __restrict__ Wfc,
    unsigned short* __restrict__ ws)
{
    const int l  = (int)threadIdx.x;
    const int lg = l >> 4, li = l & 15;
    _Float16* waF  = (_Float16*)ws;
    _Float16* wfcF = (_Float16*)(ws + 64 * 64);
    int*      rc   = (int*)(ws + 64 * 64 + 64 * 16);
    #pragma unroll
    for (int nt = 0; nt < 4; ++nt)
        #pragma unroll
        for (int kh = 0; kh < 2; ++kh)
            #pragma unroll
            for (int i = 0; i < 8; ++i) {
                int d = kh * 32 + lg * 8 + i;
                waF[l * 64 + (nt * 2 + kh) * 8 + i] = (_Float16)Wa[d * NA + nt * 16 + li];
            }
    #pragma unroll
    for (int kh = 0; kh < 2; ++kh)
        #pragma unroll
        for (int i = 0; i < 8; ++i) {
            int d = kh * 32 + lg * 8 + i;
            float w = Wfc[d];
            _Float16 hi = (_Float16)w;
            _Float16 lo = (_Float16)(w - (float)hi);
            wfcF[l * 16 + kh * 8 + i] = (li == 0) ? hi : ((li == 1) ? lo : (_Float16)0.f);
        }
    for (int p0 = l; p0 < NPAD; p0 += 64) {
        int r = 0, c = 0;
        if (p0 < NP) {
            int rem = p0;
            while (rem >= NF - 1 - r) { rem -= NF - 1 - r; ++r; }
            c = r + 1 + rem;
        }
        rc[p0] = (r << 16) | c;
    }
}

__global__ __launch_bounds__(NT) void afm_mfma_kernel(
    const float* __restrict__ x,
    const float* __restrict__ ba,
    const float* __restrict__ Wp,
    const float* __restrict__ bfc,
    const unsigned short* __restrict__ ws,
    float* __restrict__ out)
{
    const int tid  = (int)threadIdx.x;
    const int lane = tid & 63;
    const int wid  = tid >> 6;
    const int b    = blockIdx.x * BPB + wid;   // this wave's batch
    const int lg   = lane >> 4;
    const int li   = lane & 15;

    __shared__ _Float16 xs[BPB][NF][XPITCH];   // per-wave fp16 x tile
    __shared__ float    lsums[BPB][NPAD][4];   // per-pair partial logits by lg
    __shared__ float    vvs[BPB][NPAD];        // per-pair v (written by lg0)

    // ---- stage x[b] into LDS as fp16 (cvt once here) ----
    const float4* xb4 = (const float4*)(x + (size_t)b * (NF * ND));
    #pragma unroll
    for (int k = 0; k < 6; ++k) {
        int i = lane + k * 64;           // 0..383 float4s
        float4 v = xb4[i];
        f16x4 hv = { (_Float16)v.x, (_Float16)v.y, (_Float16)v.z, (_Float16)v.w };
        *(f16x4*)&xs[wid][i >> 4][(i & 15) * 4] = hv;   // 8B-aligned
    }

    // ---- fragments from ws: 10 vector loads, no cvt ----
    const f16x8* waF  = (const f16x8*)ws;              // [64][8]
    const f16x8* wfcF = (const f16x8*)(ws + 64 * 64);  // [64][2]
    const int*   rcg  = (const int*)(ws + 64 * 64 + 64 * 16);
    f16x8 WaF[4][2];
    #pragma unroll
    for (int nt = 0; nt < 4; ++nt)
        #pragma unroll
        for (int kh = 0; kh < 2; ++kh)
            WaF[nt][kh] = waF[lane * 8 + nt * 2 + kh];
    f16x8 WfcF[2] = { wfcF[lane * 2 + 0], wfcF[lane * 2 + 1] };

    // per-lane unit arrays: unit = nt*16 + lg*4 + j  (C/D row under swapped MFMA)
    float ba_t[4][4], wp_t[4][4];
    #pragma unroll
    for (int nt = 0; nt < 4; ++nt)
        #pragma unroll
        for (int j = 0; j < 4; ++j) {
            ba_t[nt][j] = ba[nt * 16 + lg * 4 + j];
            wp_t[nt][j] = Wp[nt * 16 + lg * 4 + j];
        }

    // hoisted pair table (18 ints)
    int prt[NTILE];
    #pragma unroll
    for (int t = 0; t < NTILE; ++t) prt[t] = rcg[t * 16 + li];

    // in-wave ordering of staging writes vs tile reads
    asm volatile("s_waitcnt lgkmcnt(0)" ::: "memory");

    // ---- skewed pipeline: MFMAs of tile t in flight while epilogue of t-1 runs ----
    f32x4 accP[4], accvP;

    // prologue: tile 0 loads + MFMAs -> accP
    {
        int pr = prt[0];
        int rI = pr >> 16, cI = pr & 0xffff;
        f16x8 Ah[2];
        #pragma unroll
        for (int kh = 0; kh < 2; ++kh) {
            int d0 = kh * 32 + lg * 8;
            f16x8 rv = *(const f16x8*)&xs[wid][rI][d0];
            f16x8 cv = *(const f16x8*)&xs[wid][cI][d0];
            Ah[kh] = rv * cv;
        }
        #pragma unroll
        for (int nt = 0; nt < 4; ++nt) {
            accP[nt] = (f32x4){ba_t[nt][0], ba_t[nt][1], ba_t[nt][2], ba_t[nt][3]};
            accP[nt] = __builtin_amdgcn_mfma_f32_16x16x32_f16(WaF[nt][0], Ah[0], accP[nt], 0, 0, 0);
            accP[nt] = __builtin_amdgcn_mfma_f32_16x16x32_f16(WaF[nt][1], Ah[1], accP[nt], 0, 0, 0);
        }
        accvP = (f32x4){0.f, 0.f, 0.f, 0.f};
        accvP = __builtin_amdgcn_mfma_f32_16x16x32_f16(WfcF[0], Ah[0], accvP, 0, 0, 0);
        accvP = __builtin_amdgcn_mfma_f32_16x16x32_f16(WfcF[1], Ah[1], accvP, 0, 0, 0);
    }

    #pragma unroll
    for (int t = 1; t <= NTILE; ++t) {
        f32x4 accC[4], accvC;
        if (t < NTILE) {
            // issue tile t loads + MFMAs
            int pr = prt[t];
            int rI = pr >> 16, cI = pr & 0xffff;
            f16x8 Ah[2];
            #pragma unroll
            for (int kh = 0; kh < 2; ++kh) {
                int d0 = kh * 32 + lg * 8;
                f16x8 rv = *(const f16x8*)&xs[wid][rI][d0];
                f16x8 cv = *(const f16x8*)&xs[wid][cI][d0];
                Ah[kh] = rv * cv;
            }
            #pragma unroll
            for (int nt = 0; nt < 4; ++nt) {
                accC[nt] = (f32x4){ba_t[nt][0], ba_t[nt][1], ba_t[nt][2], ba_t[nt][3]};
                accC[nt] = __builtin_amdgcn_mfma_f32_16x16x32_f16(WaF[nt][0], Ah[0], accC[nt], 0, 0, 0);
                accC[nt] = __builtin_amdgcn_mfma_f32_16x16x32_f16(WaF[nt][1], Ah[1], accC[nt], 0, 0, 0);
            }
            accvC = (f32x4){0.f, 0.f, 0.f, 0.f};
            accvC = __builtin_amdgcn_mfma_f32_16x16x32_f16(WfcF[0], Ah[0], accvC, 0, 0, 0);
            accvC = __builtin_amdgcn_mfma_f32_16x16x32_f16(WfcF[1], Ah[1], accvC, 0, 0, 0);
        }

        // epilogue for tile t-1 (accP), overlapped with tile t MFMAs:
        // tree-reduced relu+Wp dot over this lane's 16 units
        {
            float s0 = 0.f, s1 = 0.f, s2 = 0.f, s3 = 0.f;
            #pragma unroll
            for (int j = 0; j < 4; ++j) {
                s0 = fmaf(fmaxf(accP[0][j], 0.f), wp_t[0][j], s0);
                s1 = fmaf(fmaxf(accP[1][j], 0.f), wp_t[1][j], s1);
                s2 = fmaf(fmaxf(accP[2][j], 0.f), wp_t[2][j], s2);
                s3 = fmaf(fmaxf(accP[3][j], 0.f), wp_t[3][j], s3);
            }
            float lsum = (s0 + s1) + (s2 + s3);
            int row = (t - 1) * 16 + li;
            lsums[wid][row][lg] = lsum;          // 2 lanes/bank: conflict-free
            if (lg == 0)
                vvs[wid][row] = accvP[0] + accvP[1];   // rows 0(hi)+1(lo)
        }

        if (t < NTILE) {
            #pragma unroll
            for (int nt = 0; nt < 4; ++nt) accP[nt] = accC[nt];
            accvP = accvC;
        }
    }

    asm volatile("s_waitcnt lgkmcnt(0)" ::: "memory");

    // ---- per-wave softmax fused with output (combine lg-partials here) ----
    float2 myv[5];
    float m = -INFINITY;
    #pragma unroll
    for (int k = 0; k < 5; ++k) {
        int p = lane + k * 64;
        if (p < NP) {
            float4 ls = *(const float4*)&lsums[wid][p][0];
            float lg4 = (ls.x + ls.y) + (ls.z + ls.w);
            myv[k] = make_float2(lg4, vvs[wid][p]);
            m = fmaxf(m, lg4);
        } else {
            myv[k] = make_float2(-INFINITY, 0.f);
        }
    }
    m = wave_max(m);

    float se = 0.f, sev = 0.f;
    #pragma unroll
    for (int k = 0; k < 5; ++k) {
        int p = lane + k * 64;
        if (p < NP) {
            float e = __expf(myv[k].x - m);
            se += e;
            sev = fmaf(e, myv[k].y, sev);
        }
    }
    se  = wave_sum(se);
    sev = wave_sum(sev);
    if (lane == 0)
        out[b] = sev / se + bfc[0];
}

extern "C" void kernel_launch(void* const* d_in, const int* in_sizes, int n_in,
                              void* d_out, int out_size, void* d_ws, size_t ws_size,
                              hipStream_t stream) {
    const float* x   = (const float*)d_in[0];
    const float* Wa  = (const float*)d_in[1];
    const float* ba  = (const float*)d_in[2];
    const float* Wp  = (const float*)d_in[3];
    // d_in[4] = bp  (unused: softmax shift-invariant)
    const float* Wfc = (const float*)d_in[5];
    const float* bfc = (const float*)d_in[6];
    float* out = (float*)d_out;
    unsigned short* ws = (unsigned short*)d_ws;

    const int B = in_sizes[0] / (NF * ND);
    hipLaunchKernelGGL(afm_prep_kernel, dim3(1), dim3(64), 0, stream, Wa, Wfc, ws);
    hipLaunchKernelGGL(afm_mfma_kernel, dim3(B / BPB), dim3(NT), 0, stream,
                       x, ba, Wp, bfc, ws, out);
}